// Round 1
// baseline (549.553 us; speedup 1.0000x reference)
//
#include <hip/hip_runtime.h>
#include <hip/hip_bf16.h>

// ---------------------------------------------------------------------------
// UpsdHyper: out = relu-chain of per-sample hypernetwork layers.
// Y[b,o] = Σ_d c[b,d]·(Σ_h act[b,h]·W[d,h,o]) + Σ_h act[b,h]·hwb[h,o] + bias
// Main GEMM: A = act (bf16), B = W_d slices (fp32->bf16 staged in LDS),
// per-d scale applied on accumulator fragments. Split-K by d-groups of 4,
// partials reduced (+bias GEMM +ReLU) in an epilogue kernel.
// ---------------------------------------------------------------------------

typedef __bf16 bf16x8 __attribute__((ext_vector_type(8)));
typedef float  f32x4  __attribute__((ext_vector_type(4)));

#define LDS_PITCH 72   // 64 + 8: 144B rows, 16B-aligned for ds_read_b128

// ---------------------------------------------------------------------------
// embed: act0[b,j] = bf16(tanh(state @ embed_w + embed_b))   [512,512]
// grid 128 x 512thr: 4 rows per block, thread = output column (coalesced ew).
// ---------------------------------------------------------------------------
__global__ __launch_bounds__(512) void embed_kernel(
    const float* __restrict__ state,   // [512,256]
    const float* __restrict__ ew,      // [256,512]
    const float* __restrict__ eb,      // [512]
    __bf16* __restrict__ act0)         // [512,512] bf16
{
    const int o  = threadIdx.x;
    const int r0 = blockIdx.x * 4;
    float bias = eb[o];
    float acc[4] = {bias, bias, bias, bias};
    for (int s = 0; s < 256; ++s) {
        float wv = ew[s * 512 + o];
        #pragma unroll
        for (int r = 0; r < 4; ++r)
            acc[r] = fmaf(state[(r0 + r) * 256 + s], wv, acc[r]);
    }
    #pragma unroll
    for (int r = 0; r < 4; ++r)
        act0[(r0 + r) * 512 + o] = (__bf16)tanhf(acc[r]);
}

// ---------------------------------------------------------------------------
// Main hyper-GEMM. Block = (n-tile nt in 0..7, d-group g in 0..31).
// Tile: M=512 (full), N=64, K per iter = 64.  8 waves, wave-tile 64x64.
// Groups g<8 do one extra iteration that adds the hw_b GEMM term (scale=1).
// Writes partial[g][512][512-col-slice].
// ---------------------------------------------------------------------------
__global__ __launch_bounds__(512, 2) void hyper_gemm(
    const float* __restrict__ Wl,      // layer base of hw_W: [128][512][512]
    const float* __restrict__ hwbl,    // layer base of hw_b: [512][512] (h,o)
    const float* __restrict__ cmd,     // command [512][128]
    const __bf16* __restrict__ act,    // [512][512] bf16
    float* __restrict__ partial)       // [32][512][512]
{
    __shared__ __bf16 lds[2][64][LDS_PITCH];   // Wt[o][h] transposed, bf16

    const int nt   = blockIdx.x;        // 0..7
    const int g    = blockIdx.y;        // 0..31
    const int n0   = nt * 64;
    const int tid  = threadIdx.x;
    const int lane = tid & 63;
    const int wv   = tid >> 6;          // wave 0..7, owns rows [wv*64, wv*64+64)
    const int l15  = lane & 15;
    const int lg   = lane >> 4;
    const int m_base = wv * 64;

    const int sr = tid >> 4;            // staging row 0..31 (h within tile)
    const int so = (tid & 15) * 4;      // staging col group (o within tile)

    const int nit = 32 + (g < 8 ? 1 : 0);

    f32x4 Yacc[4][4];
    f32x4 Gacc[4][4];
    #pragma unroll
    for (int a = 0; a < 4; ++a)
        #pragma unroll
        for (int b = 0; b < 4; ++b) { Yacc[a][b] = (f32x4)0.f; Gacc[a][b] = (f32x4)0.f; }

    // ---- prologue: stage iteration 0 ----
    {
        const float* p = Wl + (size_t)(g << 2) * 262144 + n0;  // i=0: d=g*4, h0=0
        f32x4 va = *(const f32x4*)(p + sr * 512 + so);
        f32x4 vb = *(const f32x4*)(p + (sr + 32) * 512 + so);
        #pragma unroll
        for (int q = 0; q < 4; ++q) {
            lds[0][so + q][sr]      = (__bf16)va[q];
            lds[0][so + q][sr + 32] = (__bf16)vb[q];
        }
    }
    __syncthreads();

    int cur = 0;
    for (int i = 0; i < nit; ++i) {
        const bool hn = (i + 1 < nit);
        f32x4 na, nb;
        if (hn) {   // issue next-tile global loads early (hide under MFMA)
            const int j = i + 1;
            const float* p;
            if (j < 32) {
                int d  = (g << 2) + (j >> 3);
                int h0 = (j & 7) << 6;
                p = Wl + (size_t)d * 262144 + (size_t)h0 * 512 + n0;
            } else {
                p = hwbl + (size_t)(g << 6) * 512 + n0;
            }
            na = *(const f32x4*)(p + sr * 512 + so);
            nb = *(const f32x4*)(p + (sr + 32) * 512 + so);
        }

        const int h0 = (i < 32) ? ((i & 7) << 6) : (g << 6);

        // ---- compute current tile from lds[cur] ----
        #pragma unroll
        for (int kk = 0; kk < 2; ++kk) {
            bf16x8 afr[4], bfr[4];
            #pragma unroll
            for (int mi = 0; mi < 4; ++mi)
                afr[mi] = *(const bf16x8*)(act + (m_base + mi * 16 + l15) * 512
                                               + h0 + kk * 32 + lg * 8);
            #pragma unroll
            for (int ni = 0; ni < 4; ++ni)
                bfr[ni] = *(const bf16x8*)(&lds[cur][ni * 16 + l15][kk * 32 + lg * 8]);
            #pragma unroll
            for (int mi = 0; mi < 4; ++mi)
                #pragma unroll
                for (int ni = 0; ni < 4; ++ni)
                    Gacc[mi][ni] = __builtin_amdgcn_mfma_f32_16x16x32_bf16(
                        afr[mi], bfr[ni], Gacc[mi][ni], 0, 0, 0);
        }

        // ---- d-boundary: Y += c[m,d] * G ; G = 0 ----
        if (i < 32) {
            if ((i & 7) == 7) {
                const int d = (g << 2) + (i >> 3);
                #pragma unroll
                for (int mi = 0; mi < 4; ++mi) {
                    float cv[4];
                    #pragma unroll
                    for (int r = 0; r < 4; ++r)
                        cv[r] = cmd[(m_base + mi * 16 + lg * 4 + r) * 128 + d];
                    #pragma unroll
                    for (int ni = 0; ni < 4; ++ni)
                        #pragma unroll
                        for (int r = 0; r < 4; ++r) {
                            Yacc[mi][ni][r] = fmaf(cv[r], Gacc[mi][ni][r], Yacc[mi][ni][r]);
                            Gacc[mi][ni][r] = 0.f;
                        }
                }
            }
        } else {  // hw_b extra iteration: scale = 1
            #pragma unroll
            for (int mi = 0; mi < 4; ++mi)
                #pragma unroll
                for (int ni = 0; ni < 4; ++ni)
                    #pragma unroll
                    for (int r = 0; r < 4; ++r) {
                        Yacc[mi][ni][r] += Gacc[mi][ni][r];
                        Gacc[mi][ni][r] = 0.f;
                    }
        }

        __syncthreads();
        if (hn) {
            #pragma unroll
            for (int q = 0; q < 4; ++q) {
                lds[cur ^ 1][so + q][sr]      = (__bf16)na[q];
                lds[cur ^ 1][so + q][sr + 32] = (__bf16)nb[q];
            }
        }
        __syncthreads();
        cur ^= 1;
    }

    // ---- write partial[g] (exclusive slice: all m, cols n0..n0+63) ----
    float* pp = partial + (size_t)g * 262144 + n0;
    #pragma unroll
    for (int mi = 0; mi < 4; ++mi)
        #pragma unroll
        for (int r = 0; r < 4; ++r) {
            int m = m_base + mi * 16 + lg * 4 + r;
            #pragma unroll
            for (int ni = 0; ni < 4; ++ni)
                pp[m * 512 + ni * 16 + l15] = Yacc[mi][ni][r];
        }
}

// ---------------------------------------------------------------------------
// epilogue: out = relu(Σ_g partial[g] + c@hb_W + hb_b); writes bf16 act for
// the next layer OR fp32 final output.
// grid 256 x 512thr: 2 rows/block, thread = column.
// ---------------------------------------------------------------------------
__global__ __launch_bounds__(512) void epilogue_kernel(
    const float* __restrict__ partial,   // [32][512][512]
    const float* __restrict__ cmd,       // [512][128]
    const float* __restrict__ hbWl,      // layer base of hb_W: [128][512]
    const float* __restrict__ hbbl,      // layer base of hb_b: [512]
    __bf16* __restrict__ act_out,        // next-layer activation (or null)
    float* __restrict__ final_out)       // final output (or null)
{
    const int o  = threadIdx.x;
    const int r0 = blockIdx.x * 2;
    float a0 = hbbl[o];
    float a1 = a0;
    for (int d = 0; d < 128; ++d) {
        float wv = hbWl[d * 512 + o];
        a0 = fmaf(cmd[r0 * 128 + d],       wv, a0);
        a1 = fmaf(cmd[(r0 + 1) * 128 + d], wv, a1);
    }
    for (int s = 0; s < 32; ++s) {
        a0 += partial[((size_t)s * 512 + r0)     * 512 + o];
        a1 += partial[((size_t)s * 512 + r0 + 1) * 512 + o];
    }
    a0 = fmaxf(a0, 0.f);
    a1 = fmaxf(a1, 0.f);
    if (act_out) {
        act_out[r0 * 512 + o]       = (__bf16)a0;
        act_out[(r0 + 1) * 512 + o] = (__bf16)a1;
    } else {
        final_out[r0 * 512 + o]       = a0;
        final_out[(r0 + 1) * 512 + o] = a1;
    }
}

// ---------------------------------------------------------------------------
extern "C" void kernel_launch(void* const* d_in, const int* in_sizes, int n_in,
                              void* d_out, int out_size, void* d_ws, size_t ws_size,
                              hipStream_t stream) {
    const float* state = (const float*)d_in[0];   // [512,256]
    const float* cmd   = (const float*)d_in[1];   // [512,128]
    const float* ew    = (const float*)d_in[2];   // [256,512]
    const float* eb    = (const float*)d_in[3];   // [512]
    const float* hwW   = (const float*)d_in[4];   // [2,128,262144]
    const float* hwb   = (const float*)d_in[5];   // [2,262144]
    const float* hbW   = (const float*)d_in[6];   // [2,128,512]
    const float* hbb   = (const float*)d_in[7];   // [2,512]
    float* out = (float*)d_out;

    char* ws = (char*)d_ws;
    __bf16* act0   = (__bf16*)ws;                        // 512 KB
    __bf16* act1   = (__bf16*)(ws + 512 * 1024);         // 512 KB
    float*  partial = (float*)(ws + 1024 * 1024);        // 32 MB

    embed_kernel<<<128, 512, 0, stream>>>(state, ew, eb, act0);

    // layer 0
    hyper_gemm<<<dim3(8, 32), 512, 0, stream>>>(
        hwW, hwb, cmd, act0, partial);
    epilogue_kernel<<<256, 512, 0, stream>>>(
        partial, cmd, hbW, hbb, act1, nullptr);

    // layer 1
    hyper_gemm<<<dim3(8, 32), 512, 0, stream>>>(
        hwW + (size_t)128 * 262144, hwb + 262144, cmd, act1, partial);
    epilogue_kernel<<<256, 512, 0, stream>>>(
        partial, cmd, hbW + 128 * 512, hbb + 512, nullptr, out);
}